// Round 1
// baseline (233.431 us; speedup 1.0000x reference)
//
#include <hip/hip_runtime.h>

// Problem constants (fixed by setup_inputs): B=8, S=4096, H=1024
constexpr int Bn  = 8;
constexpr int Sn  = 4096;
constexpr int Nn  = Bn * Sn;          // 32768 labels
constexpr int Hn  = 1024;

constexpr int TPB = 256;              // block size (copy blocks and scan block)
constexpr int NW  = TPB / 64;         // 4 waves in scan block
constexpr int G4    = Nn / 4;         // 8192 int4 label groups
constexpr int ITERS = G4 / TPB;       // 32 coalesced iterations over labels

constexpr size_t FEAT_ELEMS = (size_t)Nn * Hn;        // 33,554,432 floats
constexpr size_t FEAT_VEC4  = FEAT_ELEMS / 4;         // 8,388,608 float4
constexpr int    VEC_PER_T  = 8;                      // float4 per copy thread
constexpr int    COPY_BLOCKS = (int)(FEAT_VEC4 / ((size_t)TPB * VEC_PER_T)); // 4096

// Native clang vector type — required by __builtin_nontemporal_load/store
typedef float v4f __attribute__((ext_vector_type(4)));

// Fused kernel:
//   block 0:                 COALESCED single-block scan producing segment ids.
//                            (Previous version: per-thread-contiguous label
//                            ownership -> every memory op was a 64-lane scatter
//                            at 512B stride; pass 2 was 128 scalar scattered
//                            stores/thread. That made block 0 the straggler.)
//                            Now: half-wave-per-range counting with coalesced
//                            int4 loads + shfl prefix + coalesced float4 NT emit.
//   blocks [1, COPY_BLOCKS]: each copies one CONTIGUOUS 32 KB chunk (unchanged).
__global__ __launch_bounds__(TPB) void fused_kernel(const float* __restrict__ seq,
                                                    const int* __restrict__ labels,
                                                    float* __restrict__ out) {
    if (blockIdx.x > 0) {
        const v4f* __restrict__ src = reinterpret_cast<const v4f*>(seq);
        v4f* __restrict__ dst       = reinterpret_cast<v4f*>(out);
        const size_t base = (size_t)(blockIdx.x - 1) * (TPB * VEC_PER_T) + threadIdx.x;
        v4f r[VEC_PER_T];
#pragma unroll
        for (int i = 0; i < VEC_PER_T; ++i)
            r[i] = __builtin_nontemporal_load(&src[base + (size_t)i * TPB]);
#pragma unroll
        for (int i = 0; i < VEC_PER_T; ++i)
            __builtin_nontemporal_store(r[i], &dst[base + (size_t)i * TPB]);
        return;
    }

    // ---- scan part (block 0): all 32768 segment ids, fully coalesced ----
    // range r (r = 0..255) = labels [r*128, r*128+128) = int4 groups [r*32, r*32+32)
    __shared__ int range_pre[TPB];     // per-range zero counts -> exclusive offsets
    __shared__ int wave_sums[NW];
    __shared__ int extra_off_sh[Bn];

    const int tid  = threadIdx.x;
    const int lane = tid & 63;
    const int hl   = lane & 31;        // lane within 32-lane half-wave
    const int wave = tid >> 6;

    const int4* __restrict__ lab4 = reinterpret_cast<const int4*>(labels);
    v4f* __restrict__ seg4 = reinterpret_cast<v4f*>(out + FEAT_ELEMS);

    // Pass 1: coalesced zero-counting. Each iteration the block reads 256
    // consecutive int4 (4 KB contiguous); each 32-lane half-wave covers
    // exactly one range (32 consecutive int4 = 128 labels).
#pragma unroll 4
    for (int i = 0; i < ITERS; ++i) {
        const int g = i * TPB + tid;
        int4 v = lab4[g];
        int c = (v.x == 0) + (v.y == 0) + (v.z == 0) + (v.w == 0);
#pragma unroll
        for (int k = 1; k < 32; k <<= 1) c += __shfl_xor(c, k, 32);
        if (hl == 0) range_pre[g >> 5] = c;   // g>>5 = range id, unique writer
    }

    // Tiny serial job: exclusive scan of the 8 per-example "extra" bits
    if (tid == 0) {
        int acc = 0;
#pragma unroll
        for (int b = 0; b < Bn; ++b) {
            extra_off_sh[b] = acc;
            acc += (labels[b * Sn + Sn - 1] == 1);
        }
    }
    __syncthreads();

    // Thread-level scan of the 256 range sums (wave scan + cross-wave fixup)
    const int s = range_pre[tid];
    int incl = s;
#pragma unroll
    for (int off = 1; off < 64; off <<= 1) {
        int u = __shfl_up(incl, off, 64);
        if (lane >= off) incl += u;
    }
    if (lane == 63) wave_sums[wave] = incl;
    __syncthreads();

    if (wave == 0) {
        int v = (lane < NW) ? wave_sums[lane] : 0;
#pragma unroll
        for (int off = 1; off < NW; off <<= 1) {
            int u = __shfl_up(v, off, 64);
            if (lane >= off) v += u;
        }
        if (lane < NW) wave_sums[lane] = v;
    }
    __syncthreads();

    // exclusive zero-count before range tid; in-place (own slot only)
    range_pre[tid] = (wave ? wave_sums[wave - 1] : 0) + (incl - s);
    __syncthreads();

    // Pass 2: coalesced emit. Re-read labels (L2-hot), 32-lane shfl prefix
    // gives the within-range exclusive count; emit coalesced float4 NT stores.
    // Segment ids (max ~16.4k) are exact in fp32.
#pragma unroll 4
    for (int i = 0; i < ITERS; ++i) {
        const int g = i * TPB + tid;
        int4 v = lab4[g];
        const int f0 = (v.x == 0), f1 = (v.y == 0), f2 = (v.z == 0), f3 = (v.w == 0);
        const int c = f0 + f1 + f2 + f3;
        int pc = c;
#pragma unroll
        for (int off = 1; off < 32; off <<= 1) {
            int u = __shfl_up(pc, off, 32);
            if (hl >= off) pc += u;
        }
        // zeros strictly before label 4g = range offset + earlier lanes in range
        const int base = range_pre[g >> 5] + extra_off_sh[g >> 10] + (pc - c);
        v4f r;
        r.x = (float)base;
        r.y = (float)(base + f0);
        r.z = (float)(base + f0 + f1);
        r.w = (float)(base + f0 + f1 + f2);
        __builtin_nontemporal_store(r, &seg4[g]);
    }
}

extern "C" void kernel_launch(void* const* d_in, const int* in_sizes, int n_in,
                              void* d_out, int out_size, void* d_ws, size_t ws_size,
                              hipStream_t stream) {
    const float* seq    = (const float*)d_in[0];  // [B,S,H] fp32
    const int*   labels = (const int*)d_in[1];    // [B,S] int32 (harness-delivered)
    float*       out    = (float*)d_out;

    fused_kernel<<<COPY_BLOCKS + 1, TPB, 0, stream>>>(seq, labels, out);
}